// Round 2
// baseline (3274.445 us; speedup 1.0000x reference)
//
#include <hip/hip_runtime.h>
#include <hip/hip_bf16.h>
#include <math.h>

// Problem constants
#define NN 4096
#define TT 48
#define HH 64
#define GG 256   // 4*H
#define PP 12
#define CAP 160  // ELL slots per row (mean nnz ~42; 160 is >18 sigma headroom)

// ---------------------------------------------------------------------------
// Setup: zero h/c state, fold the 4 biases per cell into one 256-vector.
// ---------------------------------------------------------------------------
__launch_bounds__(256)
__global__ void k_prep(const float* gcbi0, const float* gcbh0,
                       const float* libi0, const float* libh0,
                       const float* gcbi1, const float* gcbh1,
                       const float* libi1, const float* libh1,
                       float* bias, float* state) {
  int idx = blockIdx.x * 256 + threadIdx.x;
  int stride = gridDim.x * 256;
  for (int i = idx; i < 4 * NN * HH; i += stride) state[i] = 0.0f;
  if (idx < GG) {
    bias[idx]      = gcbi0[idx] + gcbh0[idx] + libi0[idx] + libh0[idx];
    bias[GG + idx] = gcbi1[idx] + gcbh1[idx] + libi1[idx] + libh1[idx];
  }
}

// ---------------------------------------------------------------------------
// Degree: d[r] = sum(adj[r,:]) + 1 (the +I diagonal); dinv = d^-0.5
// ---------------------------------------------------------------------------
__launch_bounds__(256)
__global__ void k_deg(const float* adj, float* dinv) {
  int r = blockIdx.x;
  __shared__ float red[256];
  const float* row = adj + (size_t)r * NN;
  float s = 0.0f;
  for (int c = threadIdx.x; c < NN; c += 256) s += row[c];
  red[threadIdx.x] = s;
  __syncthreads();
  for (int st = 128; st > 0; st >>= 1) {
    if (threadIdx.x < st) red[threadIdx.x] += red[threadIdx.x + st];
    __syncthreads();
  }
  if (threadIdx.x == 0) {
    float d = red[0] + 1.0f;  // always > 0
    dinv[r] = 1.0f / sqrtf(d);
  }
}

// ---------------------------------------------------------------------------
// Build normalized ELLPACK of A = dinv*(adj+I)*dinv. Slot order within a row
// is arbitrary (sum order differences are ~1e-7 relative, far under tol).
// ---------------------------------------------------------------------------
__launch_bounds__(256)
__global__ void k_ell(const float* adj, const float* dinv,
                      int* ell_col, float* ell_val, int* ell_cnt) {
  int r = blockIdx.x;
  __shared__ int cnt;
  if (threadIdx.x == 0) cnt = 0;
  __syncthreads();
  float dr = dinv[r];
  const float* row = adj + (size_t)r * NN;
  for (int c = threadIdx.x; c < NN; c += 256) {
    float a = row[c];
    if (c == r) a += 1.0f;
    if (a != 0.0f) {
      int pos = atomicAdd(&cnt, 1);
      if (pos < CAP) {
        ell_col[(size_t)r * CAP + pos] = c;
        ell_val[(size_t)r * CAP + pos] = dr * a * dinv[c];
      }
    }
  }
  __syncthreads();
  if (threadIdx.x == 0) ell_cnt[r] = cnt < CAP ? cnt : CAP;
}

// ---------------------------------------------------------------------------
// Cell phase A: Z = [x-part +] u1@Wz1 [+ u2@Wz2]
//              L = [x-part +] u1@Wl1 [+ u2@Wl2] + bias
// 8 rows x 256 cols per block; u-tiles in LDS read as float4 (ds_read_b128).
// ---------------------------------------------------------------------------
template <bool HASX, bool HASU2>
__launch_bounds__(256)
__global__ void k_cellA(const float* __restrict__ u1, const float* __restrict__ u2,
                        const float* __restrict__ Wz1, const float* __restrict__ Wz2,
                        const float* __restrict__ Wl1, const float* __restrict__ Wl2,
                        const float* __restrict__ xt,    // [N][2], only HASX
                        const float* __restrict__ xWz,   // [2][256]
                        const float* __restrict__ xWl,   // [2][256]
                        const float* __restrict__ bias,  // [256]
                        float* __restrict__ Z, float* __restrict__ L) {
  const int col = threadIdx.x;
  const int row0 = blockIdx.x * 8;
  __shared__ float u1s[8][64];
  __shared__ float u2s[8][64];
  __shared__ float xs[8][2];

  for (int i = threadIdx.x; i < 8 * 64; i += 256) {
    int rr = i >> 6, kk = i & 63;
    u1s[rr][kk] = u1[(size_t)(row0 + rr) * HH + kk];
    if (HASU2) u2s[rr][kk] = u2[(size_t)(row0 + rr) * HH + kk];
  }
  if (HASX && threadIdx.x < 16) {
    int rr = threadIdx.x >> 1, ii = threadIdx.x & 1;
    xs[rr][ii] = xt[(size_t)(row0 + rr) * 2 + ii];
  }
  __syncthreads();

  float accZ[8], accL[8];
  float bz = bias[col];
  if (HASX) {
    float w0z = xWz[col], w1z = xWz[256 + col];
    float w0l = xWl[col], w1l = xWl[256 + col];
#pragma unroll
    for (int r = 0; r < 8; r++) {
      accZ[r] = xs[r][0] * w0z + xs[r][1] * w1z;
      accL[r] = xs[r][0] * w0l + xs[r][1] * w1l + bz;
    }
  } else {
#pragma unroll
    for (int r = 0; r < 8; r++) { accZ[r] = 0.0f; accL[r] = bz; }
  }

  for (int k = 0; k < 64; k += 4) {
    float wz1[4], wl1[4], wz2[4], wl2[4];
#pragma unroll
    for (int i = 0; i < 4; i++) {
      wz1[i] = Wz1[(k + i) * GG + col];
      wl1[i] = Wl1[(k + i) * GG + col];
      if (HASU2) {
        wz2[i] = Wz2[(k + i) * GG + col];
        wl2[i] = Wl2[(k + i) * GG + col];
      }
    }
#pragma unroll
    for (int r = 0; r < 8; r++) {
      float4 u1v = *reinterpret_cast<const float4*>(&u1s[r][k]);
      accZ[r] += u1v.x * wz1[0] + u1v.y * wz1[1] + u1v.z * wz1[2] + u1v.w * wz1[3];
      accL[r] += u1v.x * wl1[0] + u1v.y * wl1[1] + u1v.z * wl1[2] + u1v.w * wl1[3];
      if (HASU2) {
        float4 u2v = *reinterpret_cast<const float4*>(&u2s[r][k]);
        accZ[r] += u2v.x * wz2[0] + u2v.y * wz2[1] + u2v.z * wz2[2] + u2v.w * wz2[3];
        accL[r] += u2v.x * wl2[0] + u2v.y * wl2[1] + u2v.z * wl2[2] + u2v.w * wl2[3];
      }
    }
  }
#pragma unroll
  for (int r = 0; r < 8; r++) {
    Z[(size_t)(row0 + r) * GG + col] = accZ[r];
    L[(size_t)(row0 + r) * GG + col] = accL[r];
  }
}

// ---------------------------------------------------------------------------
// Cell phase B: comb[r,:] = sum_j A[r,cj]*Z[cj,:] + L[r,:]; LSTM gate update.
// One block per row; gather of Z rows is 1KB coalesced per nnz.
// ---------------------------------------------------------------------------
__launch_bounds__(256)
__global__ void k_cellB(const int* __restrict__ ell_col, const float* __restrict__ ell_val,
                        const int* __restrict__ ell_cnt,
                        const float* __restrict__ Z, const float* __restrict__ L,
                        float* __restrict__ h, float* __restrict__ c) {
  int r = blockIdx.x;
  int tid = threadIdx.x;
  __shared__ int cols[CAP];
  __shared__ float vals[CAP];
  __shared__ float comb[GG];
  int cnt = ell_cnt[r];
  if (tid < cnt) {
    cols[tid] = ell_col[(size_t)r * CAP + tid];
    vals[tid] = ell_val[(size_t)r * CAP + tid];
  }
  __syncthreads();
  float acc = 0.0f;
  for (int j = 0; j < cnt; j++) {
    acc += vals[j] * Z[(size_t)cols[j] * GG + tid];
  }
  comb[tid] = acc + L[(size_t)r * GG + tid];
  __syncthreads();
  if (tid < HH) {
    float ig = comb[tid];
    float fg = comb[tid + 64];
    float og = comb[tid + 128];
    float gg = comb[tid + 192];
    float cprev = c[(size_t)r * HH + tid];
    float si = 1.0f / (1.0f + __expf(-ig));
    float sf = 1.0f / (1.0f + __expf(-fg));
    float so = 1.0f / (1.0f + __expf(-og));
    float cn = sf * cprev + si * tanhf(gg);
    float hn = so * tanhf(cn);
    c[(size_t)r * HH + tid] = cn;
    h[(size_t)r * HH + tid] = hn;
  }
}

// ---------------------------------------------------------------------------
// Output projection: out[r,p] = h1[r,:] @ outW[:,p] + outb[p].
// ---------------------------------------------------------------------------
__launch_bounds__(256)
__global__ void k_out(const float* __restrict__ h1, const float* __restrict__ outW,
                      const float* __restrict__ outb, float* __restrict__ out) {
  int idx = blockIdx.x * 256 + threadIdx.x;
  if (idx >= NN * PP) return;
  int r = idx / PP, p = idx - r * PP;
  float acc = outb[p];
  const float* hrow = h1 + (size_t)r * HH;
#pragma unroll 16
  for (int k = 0; k < HH; k++) acc += hrow[k] * outW[k * PP + p];
  out[idx] = acc;
}

extern "C" void kernel_launch(void* const* d_in, const int* in_sizes, int n_in,
                              void* d_out, int out_size, void* d_ws, size_t ws_size,
                              hipStream_t stream) {
  const float* x     = (const float*)d_in[0];
  const float* adj   = (const float*)d_in[1];
  const float* gcWi0 = (const float*)d_in[2];
  const float* gcbi0 = (const float*)d_in[3];
  const float* gcWh0 = (const float*)d_in[4];
  const float* gcbh0 = (const float*)d_in[5];
  const float* liWi0 = (const float*)d_in[6];
  const float* libi0 = (const float*)d_in[7];
  const float* liWh0 = (const float*)d_in[8];
  const float* libh0 = (const float*)d_in[9];
  const float* gcWi1 = (const float*)d_in[10];
  const float* gcbi1 = (const float*)d_in[11];
  const float* gcWh1 = (const float*)d_in[12];
  const float* gcbh1 = (const float*)d_in[13];
  const float* liWi1 = (const float*)d_in[14];
  const float* libi1 = (const float*)d_in[15];
  const float* liWh1 = (const float*)d_in[16];
  const float* libh1 = (const float*)d_in[17];
  const float* outW  = (const float*)d_in[18];
  const float* outb  = (const float*)d_in[19];

  // workspace carve-up (all fp32/int32, ~14 MB total)
  char* ws = (char*)d_ws;
  size_t off = 0;
  auto carve = [&](size_t bytes) {
    void* p = ws + off;
    off += (bytes + 255) & ~(size_t)255;
    return p;
  };
  float* dinv    = (float*)carve((size_t)NN * 4);
  int*   ell_col = (int*)carve((size_t)NN * CAP * 4);
  float* ell_val = (float*)carve((size_t)NN * CAP * 4);
  int*   ell_cnt = (int*)carve((size_t)NN * 4);
  float* bias    = (float*)carve((size_t)2 * GG * 4);
  float* state   = (float*)carve((size_t)4 * NN * HH * 4);
  float* Zbuf    = (float*)carve((size_t)NN * GG * 4);
  float* Lbuf    = (float*)carve((size_t)NN * GG * 4);

  float* h0 = state;
  float* c0 = state + NN * HH;
  float* h1 = state + 2 * NN * HH;
  float* c1 = state + 3 * NN * HH;

  k_prep<<<1024, 256, 0, stream>>>(gcbi0, gcbh0, libi0, libh0,
                                   gcbi1, gcbh1, libi1, libh1,
                                   bias, state);
  k_deg<<<NN, 256, 0, stream>>>(adj, dinv);
  k_ell<<<NN, 256, 0, stream>>>(adj, dinv, ell_col, ell_val, ell_cnt);

  for (int t = 0; t < TT; t++) {
    // cell 0: Z = x_t@gcWi0 + h0@gcWh0 ; L = x_t@liWi0 + h0@liWh0 + b0
    k_cellA<true, false><<<NN / 8, 256, 0, stream>>>(
        h0, nullptr,
        gcWh0, nullptr, liWh0, nullptr,
        x + (size_t)t * NN * 2, gcWi0, liWi0,
        bias, Zbuf, Lbuf);
    k_cellB<<<NN, 256, 0, stream>>>(ell_col, ell_val, ell_cnt, Zbuf, Lbuf, h0, c0);
    // cell 1: Z = h0@gcWi1 + h1@gcWh1 ; L = h0@liWi1 + h1@liWh1 + b1
    k_cellA<false, true><<<NN / 8, 256, 0, stream>>>(
        h0, h1,
        gcWi1, gcWh1, liWi1, liWh1,
        nullptr, nullptr, nullptr,
        bias + GG, Zbuf, Lbuf);
    k_cellB<<<NN, 256, 0, stream>>>(ell_col, ell_val, ell_cnt, Zbuf, Lbuf, h1, c1);
  }

  k_out<<<(NN * PP + 255) / 256, 256, 0, stream>>>(h1, outW, outb, (float*)d_out);
}

// Round 4
// 2695.857 us; speedup vs baseline: 1.2146x; 1.2146x over previous
//
#include <hip/hip_runtime.h>
#include <math.h>

// Problem constants
#define NN 4096
#define TT 48
#define HH 64
#define GG 256   // 4*H
#define PP 12
#define CAP 160  // ELL slots per row (mean nnz ~42; huge headroom)

// ---------------------------------------------------------------------------
// Setup: zero h/c state (6 buffers), fold the 4 biases per cell.
// state layout: h0A h0B h1A h1B c0 c1, each NN*HH floats.
// ---------------------------------------------------------------------------
__launch_bounds__(256)
__global__ void k_prep(const float* gcbi0, const float* gcbh0,
                       const float* libi0, const float* libh0,
                       const float* gcbi1, const float* gcbh1,
                       const float* libi1, const float* libh1,
                       float* bias, float* state) {
  int idx = blockIdx.x * 256 + threadIdx.x;
  int stride = gridDim.x * 256;
  for (int i = idx; i < 6 * NN * HH; i += stride) state[i] = 0.0f;
  if (idx < GG) {
    bias[idx]      = gcbi0[idx] + gcbh0[idx] + libi0[idx] + libh0[idx];
    bias[GG + idx] = gcbi1[idx] + gcbh1[idx] + libi1[idx] + libh1[idx];
  }
}

// ---------------------------------------------------------------------------
// Single adj pass: build raw ELL (a values incl. +I diag), row degree -> dinv.
// CRITICAL (re-poison semantics): d_ws is 0xAA-poisoned before every launch,
// so we zero-fill ALL CAP slots per row — any later pass that touches a slot
// we didn't write would read poison (0xAAAAAAAA as int = wild index -> fault).
// ---------------------------------------------------------------------------
__launch_bounds__(256)
__global__ void k_build(const float* adj, float* dinv,
                        int* ell_col, float* ell_val, int* ell_cnt) {
  int r = blockIdx.x;
  __shared__ int cnt;
  __shared__ float red[256];
  if (threadIdx.x == 0) cnt = 0;
  __syncthreads();
  const float* row = adj + (size_t)r * NN;
  float s = 0.0f;
  for (int c = threadIdx.x; c < NN; c += 256) {
    float a = row[c];
    if (c == r) a += 1.0f;   // A = adj + I
    s += a;
    if (a != 0.0f) {
      int pos = atomicAdd(&cnt, 1);
      if (pos < CAP) {
        ell_col[(size_t)r * CAP + pos] = c;
        ell_val[(size_t)r * CAP + pos] = a;
      }
    }
  }
  red[threadIdx.x] = s;
  __syncthreads();
  for (int st = 128; st > 0; st >>= 1) {
    if (threadIdx.x < st) red[threadIdx.x] += red[threadIdx.x + st];
    __syncthreads();
  }
  int n = cnt < CAP ? cnt : CAP;
  int npad = (n + 3) & ~3;
  if (npad > CAP) npad = CAP;
  // zero-fill every remaining slot [n, CAP)
  for (int j = n + (int)threadIdx.x; j < CAP; j += 256) {
    ell_col[(size_t)r * CAP + j] = 0;
    ell_val[(size_t)r * CAP + j] = 0.0f;
  }
  if (threadIdx.x == 0) {
    ell_cnt[r] = npad;
    dinv[r] = 1.0f / sqrtf(red[0]);  // red[0] = rowsum + 1 >= 1
  }
}

// ---------------------------------------------------------------------------
// Scale ELL values: val *= dinv[r] * dinv[col]. All slots initialized by
// k_build (padding has val=0, col=0), so the full-array pass is safe.
// ---------------------------------------------------------------------------
__launch_bounds__(256)
__global__ void k_scale(const float* dinv, const int* ell_col, float* ell_val) {
  int idx = blockIdx.x * 256 + threadIdx.x;  // over NN*CAP
  int r = idx / CAP;
  if (r >= NN) return;
  float v = ell_val[idx];
  if (v != 0.0f) ell_val[idx] = v * dinv[r] * dinv[ell_col[idx]];
}

// ---------------------------------------------------------------------------
// Precompute gax[t][r][c] = (A @ x_t)[r][c] for all 48 timesteps.
// One block per t; x_t (32KB) staged in LDS so the random column reads are
// LDS-resident.
// ---------------------------------------------------------------------------
__launch_bounds__(256)
__global__ void k_gax(const float* x, const int* ell_col, const float* ell_val,
                      const int* ell_cnt, float* gax) {
  int t = blockIdx.x;
  __shared__ float xs[NN * 2];
  const float* xt = x + (size_t)t * NN * 2;
  for (int i = threadIdx.x; i < NN * 2; i += 256) xs[i] = xt[i];
  __syncthreads();
  for (int o = threadIdx.x; o < NN * 2; o += 256) {
    int r = o >> 1, cmp = o & 1;
    int cnt = ell_cnt[r];
    const int* cp = ell_col + (size_t)r * CAP;
    const float* vp = ell_val + (size_t)r * CAP;
    float acc = 0.0f;
    for (int j = 0; j < cnt; j += 4) {
      acc += vp[j]     * xs[cp[j]     * 2 + cmp];
      acc += vp[j + 1] * xs[cp[j + 1] * 2 + cmp];
      acc += vp[j + 2] * xs[cp[j + 2] * 2 + cmp];
      acc += vp[j + 3] * xs[cp[j + 3] * 2 + cmp];
    }
    gax[(size_t)t * NN * 2 + o] = acc;
  }
}

// ---------------------------------------------------------------------------
// Cell 0, fully fused: per block of 8 rows,
//   g = (A@h0)[rows]            (gather: 256B coalesced loads per nnz)
//   comb = gax_t@gcWi + x_t@liWi + g@gcWh + h0@liWh + b   (dense, K=2+2+64+64)
//   gates -> h0', c0'           (in-kernel; h double-buffered vs gather race)
// ---------------------------------------------------------------------------
__launch_bounds__(256)
__global__ void k_cell0(const int* __restrict__ ell_col, const float* __restrict__ ell_val,
                        const int* __restrict__ ell_cnt,
                        const float* __restrict__ h0r, float* __restrict__ h0w,
                        float* __restrict__ c0,
                        const float* __restrict__ xt, const float* __restrict__ gaxt,
                        const float* __restrict__ gcWi, const float* __restrict__ liWi,
                        const float* __restrict__ gcWh, const float* __restrict__ liWh,
                        const float* __restrict__ bias) {
  const int row0 = blockIdx.x * 8;
  const int tid = threadIdx.x;
  const int wave = tid >> 6, lane = tid & 63;
  __shared__ float g0s[8][64];
  __shared__ float hs[8][64];
  __shared__ float xg[8][4];     // [rr][0..1]=x, [2..3]=gax
  __shared__ float combS[8][256];

  // --- gather phase: wave w does rows w and w+4 ---
  for (int half = 0; half < 2; half++) {
    int rr = wave + half * 4;
    int r = row0 + rr;
    int cnt = ell_cnt[r];
    const int* cp = ell_col + (size_t)r * CAP;
    const float* vp = ell_val + (size_t)r * CAP;
    float acc = 0.0f;
    for (int j = 0; j < cnt; j += 4) {
      int cA = cp[j], cB = cp[j + 1], cC = cp[j + 2], cD = cp[j + 3];
      float vA = vp[j], vB = vp[j + 1], vC = vp[j + 2], vD = vp[j + 3];
      acc += vA * h0r[(size_t)cA * HH + lane];
      acc += vB * h0r[(size_t)cB * HH + lane];
      acc += vC * h0r[(size_t)cC * HH + lane];
      acc += vD * h0r[(size_t)cD * HH + lane];
    }
    g0s[rr][lane] = acc;
  }
  // --- stage local tiles ---
  for (int i = tid; i < 512; i += 256) (&hs[0][0])[i] = h0r[(size_t)row0 * HH + i];
  if (tid < 16) {
    int rr = tid >> 1, cc = tid & 1;
    xg[rr][cc] = xt[(size_t)(row0 + rr) * 2 + cc];
    xg[rr][2 + cc] = gaxt[(size_t)(row0 + rr) * 2 + cc];
  }
  __syncthreads();

  // --- dense phase: thread = one output column, 8 rows ---
  const int col = tid;
  float acc[8];
  {
    float b = bias[col];
    float wg0 = gcWi[col], wg1 = gcWi[GG + col];
    float wl0 = liWi[col], wl1 = liWi[GG + col];
#pragma unroll
    for (int r = 0; r < 8; r++)
      acc[r] = b + xg[r][2] * wg0 + xg[r][3] * wg1 + xg[r][0] * wl0 + xg[r][1] * wl1;
  }
  for (int k = 0; k < 64; k += 4) {
    float wg[4], wl[4];
#pragma unroll
    for (int i = 0; i < 4; i++) {
      wg[i] = gcWh[(k + i) * GG + col];
      wl[i] = liWh[(k + i) * GG + col];
    }
#pragma unroll
    for (int r = 0; r < 8; r++) {
      float4 gv = *reinterpret_cast<const float4*>(&g0s[r][k]);
      float4 hv = *reinterpret_cast<const float4*>(&hs[r][k]);
      acc[r] += gv.x * wg[0] + gv.y * wg[1] + gv.z * wg[2] + gv.w * wg[3]
              + hv.x * wl[0] + hv.y * wl[1] + hv.z * wl[2] + hv.w * wl[3];
    }
  }
#pragma unroll
  for (int r = 0; r < 8; r++) combS[r][col] = acc[r];
  __syncthreads();

  // --- gate phase: 512 (row, hcol) outputs, 2 per thread, coalesced ---
#pragma unroll
  for (int p = 0; p < 2; p++) {
    int o = tid + p * 256;
    int rr = o >> 6, hc = o & 63;
    float ig = combS[rr][hc], fg = combS[rr][hc + 64];
    float og = combS[rr][hc + 128], gg = combS[rr][hc + 192];
    size_t gi = (size_t)row0 * HH + o;
    float cprev = c0[gi];
    float si = 1.0f / (1.0f + __expf(-ig));
    float sf = 1.0f / (1.0f + __expf(-fg));
    float so = 1.0f / (1.0f + __expf(-og));
    float cn = sf * cprev + si * tanhf(gg);
    float hn = so * tanhf(cn);
    c0[gi] = cn;
    h0w[gi] = hn;
  }
}

// ---------------------------------------------------------------------------
// Cell 1, fully fused: gathers A@h0_new and A@h1 (shared ELL read),
// dense K=4*64, gates -> h1', c1'.
// ---------------------------------------------------------------------------
__launch_bounds__(256)
__global__ void k_cell1(const int* __restrict__ ell_col, const float* __restrict__ ell_val,
                        const int* __restrict__ ell_cnt,
                        const float* __restrict__ h0n,
                        const float* __restrict__ h1r, float* __restrict__ h1w,
                        float* __restrict__ c1,
                        const float* __restrict__ gcWi, const float* __restrict__ liWi,
                        const float* __restrict__ gcWh, const float* __restrict__ liWh,
                        const float* __restrict__ bias) {
  const int row0 = blockIdx.x * 8;
  const int tid = threadIdx.x;
  const int wave = tid >> 6, lane = tid & 63;
  __shared__ float gis[8][64];   // A@h0n
  __shared__ float ghs[8][64];   // A@h1
  __shared__ float h0s[8][64];
  __shared__ float h1s[8][64];
  __shared__ float combS[8][256];

  for (int half = 0; half < 2; half++) {
    int rr = wave + half * 4;
    int r = row0 + rr;
    int cnt = ell_cnt[r];
    const int* cp = ell_col + (size_t)r * CAP;
    const float* vp = ell_val + (size_t)r * CAP;
    float a0 = 0.0f, a1 = 0.0f;
    for (int j = 0; j < cnt; j += 2) {
      int cA = cp[j], cB = cp[j + 1];
      float vA = vp[j], vB = vp[j + 1];
      a0 += vA * h0n[(size_t)cA * HH + lane];
      a1 += vA * h1r[(size_t)cA * HH + lane];
      a0 += vB * h0n[(size_t)cB * HH + lane];
      a1 += vB * h1r[(size_t)cB * HH + lane];
    }
    gis[rr][lane] = a0;
    ghs[rr][lane] = a1;
  }
  for (int i = tid; i < 512; i += 256) {
    (&h0s[0][0])[i] = h0n[(size_t)row0 * HH + i];
    (&h1s[0][0])[i] = h1r[(size_t)row0 * HH + i];
  }
  __syncthreads();

  const int col = tid;
  float acc[8];
  {
    float b = bias[col];
#pragma unroll
    for (int r = 0; r < 8; r++) acc[r] = b;
  }
  for (int k = 0; k < 64; k += 4) {
    float w0[4], w1[4], w2[4], w3[4];
#pragma unroll
    for (int i = 0; i < 4; i++) {
      w0[i] = gcWi[(k + i) * GG + col];
      w1[i] = liWi[(k + i) * GG + col];
      w2[i] = gcWh[(k + i) * GG + col];
      w3[i] = liWh[(k + i) * GG + col];
    }
#pragma unroll
    for (int r = 0; r < 8; r++) {
      float4 av = *reinterpret_cast<const float4*>(&gis[r][k]);
      float4 bv = *reinterpret_cast<const float4*>(&h0s[r][k]);
      float4 cv = *reinterpret_cast<const float4*>(&ghs[r][k]);
      float4 dv = *reinterpret_cast<const float4*>(&h1s[r][k]);
      acc[r] += av.x * w0[0] + av.y * w0[1] + av.z * w0[2] + av.w * w0[3]
              + bv.x * w1[0] + bv.y * w1[1] + bv.z * w1[2] + bv.w * w1[3]
              + cv.x * w2[0] + cv.y * w2[1] + cv.z * w2[2] + cv.w * w2[3]
              + dv.x * w3[0] + dv.y * w3[1] + dv.z * w3[2] + dv.w * w3[3];
    }
  }
#pragma unroll
  for (int r = 0; r < 8; r++) combS[r][col] = acc[r];
  __syncthreads();

#pragma unroll
  for (int p = 0; p < 2; p++) {
    int o = tid + p * 256;
    int rr = o >> 6, hc = o & 63;
    float ig = combS[rr][hc], fg = combS[rr][hc + 64];
    float og = combS[rr][hc + 128], gg = combS[rr][hc + 192];
    size_t gi = (size_t)row0 * HH + o;
    float cprev = c1[gi];
    float si = 1.0f / (1.0f + __expf(-ig));
    float sf = 1.0f / (1.0f + __expf(-fg));
    float so = 1.0f / (1.0f + __expf(-og));
    float cn = sf * cprev + si * tanhf(gg);
    float hn = so * tanhf(cn);
    c1[gi] = cn;
    h1w[gi] = hn;
  }
}

// ---------------------------------------------------------------------------
// Output projection: out[r,p] = h1[r,:] @ outW[:,p] + outb[p].
// ---------------------------------------------------------------------------
__launch_bounds__(256)
__global__ void k_out(const float* __restrict__ h1, const float* __restrict__ outW,
                      const float* __restrict__ outb, float* __restrict__ out) {
  int idx = blockIdx.x * 256 + threadIdx.x;
  if (idx >= NN * PP) return;
  int r = idx / PP, p = idx - r * PP;
  float acc = outb[p];
  const float* hrow = h1 + (size_t)r * HH;
#pragma unroll 16
  for (int k = 0; k < HH; k++) acc += hrow[k] * outW[k * PP + p];
  out[idx] = acc;
}

extern "C" void kernel_launch(void* const* d_in, const int* in_sizes, int n_in,
                              void* d_out, int out_size, void* d_ws, size_t ws_size,
                              hipStream_t stream) {
  const float* x     = (const float*)d_in[0];
  const float* adj   = (const float*)d_in[1];
  const float* gcWi0 = (const float*)d_in[2];
  const float* gcbi0 = (const float*)d_in[3];
  const float* gcWh0 = (const float*)d_in[4];
  const float* gcbh0 = (const float*)d_in[5];
  const float* liWi0 = (const float*)d_in[6];
  const float* libi0 = (const float*)d_in[7];
  const float* liWh0 = (const float*)d_in[8];
  const float* libh0 = (const float*)d_in[9];
  const float* gcWi1 = (const float*)d_in[10];
  const float* gcbi1 = (const float*)d_in[11];
  const float* gcWh1 = (const float*)d_in[12];
  const float* gcbh1 = (const float*)d_in[13];
  const float* liWi1 = (const float*)d_in[14];
  const float* libi1 = (const float*)d_in[15];
  const float* liWh1 = (const float*)d_in[16];
  const float* libh1 = (const float*)d_in[17];
  const float* outW  = (const float*)d_in[18];
  const float* outb  = (const float*)d_in[19];

  char* ws = (char*)d_ws;
  size_t off = 0;
  auto carve = [&](size_t bytes) {
    void* p = ws + off;
    off += (bytes + 255) & ~(size_t)255;
    return p;
  };
  float* dinv    = (float*)carve((size_t)NN * 4);
  int*   ell_col = (int*)carve((size_t)NN * CAP * 4);
  float* ell_val = (float*)carve((size_t)NN * CAP * 4);
  int*   ell_cnt = (int*)carve((size_t)NN * 4);
  float* bias    = (float*)carve((size_t)2 * GG * 4);
  float* state   = (float*)carve((size_t)6 * NN * HH * 4);
  float* gax     = (float*)carve((size_t)TT * NN * 2 * 4);

  float* h0buf[2] = {state, state + NN * HH};
  float* h1buf[2] = {state + 2 * NN * HH, state + 3 * NN * HH};
  float* c0 = state + 4 * NN * HH;
  float* c1 = state + 5 * NN * HH;

  k_prep<<<512, 256, 0, stream>>>(gcbi0, gcbh0, libi0, libh0,
                                  gcbi1, gcbh1, libi1, libh1, bias, state);
  k_build<<<NN, 256, 0, stream>>>(adj, dinv, ell_col, ell_val, ell_cnt);
  k_scale<<<(NN * CAP) / 256, 256, 0, stream>>>(dinv, ell_col, ell_val);
  k_gax<<<TT, 256, 0, stream>>>(x, ell_col, ell_val, ell_cnt, gax);

  for (int t = 0; t < TT; t++) {
    int cur = t & 1;
    k_cell0<<<NN / 8, 256, 0, stream>>>(
        ell_col, ell_val, ell_cnt,
        h0buf[cur], h0buf[cur ^ 1], c0,
        x + (size_t)t * NN * 2, gax + (size_t)t * NN * 2,
        gcWi0, liWi0, gcWh0, liWh0, bias);
    k_cell1<<<NN / 8, 256, 0, stream>>>(
        ell_col, ell_val, ell_cnt,
        h0buf[cur ^ 1],
        h1buf[cur], h1buf[cur ^ 1], c1,
        gcWi1, liWi1, gcWh1, liWh1, bias + GG);
  }

  k_out<<<(NN * PP + 255) / 256, 256, 0, stream>>>(h1buf[0], outW, outb, (float*)d_out);
}

// Round 5
// 2572.116 us; speedup vs baseline: 1.2731x; 1.0481x over previous
//
#include <hip/hip_runtime.h>
#include <math.h>

// Problem constants
#define NN 4096
#define TT 48
#define HH 64
#define GG 256   // 4*H
#define PP 12
#define CAP 192  // ELL slots per row, 3 x 64 so whole-wave chunk loads need no guard

// ---------------------------------------------------------------------------
// Setup: zero h/c state (6 buffers), fold the 4 biases per cell.
// state layout: h0A h0B h1A h1B c0 c1, each NN*HH floats.
// ---------------------------------------------------------------------------
__launch_bounds__(256)
__global__ void k_prep(const float* gcbi0, const float* gcbh0,
                       const float* libi0, const float* libh0,
                       const float* gcbi1, const float* gcbh1,
                       const float* libi1, const float* libh1,
                       float* bias, float* state) {
  int idx = blockIdx.x * 256 + threadIdx.x;
  int stride = gridDim.x * 256;
  for (int i = idx; i < 6 * NN * HH; i += stride) state[i] = 0.0f;
  if (idx < GG) {
    bias[idx]      = gcbi0[idx] + gcbh0[idx] + libi0[idx] + libh0[idx];
    bias[GG + idx] = gcbi1[idx] + gcbh1[idx] + libi1[idx] + libh1[idx];
  }
}

// ---------------------------------------------------------------------------
// Single adj pass: raw ELL (incl. +I diag) + dinv. Zero-fills ALL CAP slots
// (re-poison semantics: d_ws is 0xAA before every launch; padding must be
// (col=0, val=0) so downstream unguarded reads are safe). cnt padded to x4.
// ---------------------------------------------------------------------------
__launch_bounds__(256)
__global__ void k_build(const float* adj, float* dinv,
                        int* ell_col, float* ell_val, int* ell_cnt) {
  int r = blockIdx.x;
  __shared__ int cnt;
  __shared__ float red[256];
  if (threadIdx.x == 0) cnt = 0;
  __syncthreads();
  const float* row = adj + (size_t)r * NN;
  float s = 0.0f;
  for (int c = threadIdx.x; c < NN; c += 256) {
    float a = row[c];
    if (c == r) a += 1.0f;   // A = adj + I
    s += a;
    if (a != 0.0f) {
      int pos = atomicAdd(&cnt, 1);
      if (pos < CAP) {
        ell_col[(size_t)r * CAP + pos] = c;
        ell_val[(size_t)r * CAP + pos] = a;
      }
    }
  }
  red[threadIdx.x] = s;
  __syncthreads();
  for (int st = 128; st > 0; st >>= 1) {
    if (threadIdx.x < st) red[threadIdx.x] += red[threadIdx.x + st];
    __syncthreads();
  }
  int n = cnt < CAP ? cnt : CAP;
  // zero-fill every remaining slot [n, CAP)
  for (int j = n + (int)threadIdx.x; j < CAP; j += 256) {
    ell_col[(size_t)r * CAP + j] = 0;
    ell_val[(size_t)r * CAP + j] = 0.0f;
  }
  if (threadIdx.x == 0) {
    int npad = (n + 3) & ~3;
    if (npad > CAP) npad = CAP;
    ell_cnt[r] = npad;
    dinv[r] = 1.0f / sqrtf(red[0]);  // red[0] = rowsum + 1 >= 1
  }
}

// ---------------------------------------------------------------------------
// Scale ELL values: val *= dinv[r] * dinv[col]. All CAP slots initialized.
// ---------------------------------------------------------------------------
__launch_bounds__(256)
__global__ void k_scale(const float* dinv, const int* ell_col, float* ell_val) {
  int idx = blockIdx.x * 256 + threadIdx.x;  // over NN*CAP
  int r = idx / CAP;
  if (r >= NN) return;
  float v = ell_val[idx];
  if (v != 0.0f) ell_val[idx] = v * dinv[r] * dinv[ell_col[idx]];
}

// ---------------------------------------------------------------------------
// Precompute gax[t][r][c] = (A @ x_t)[r][c]. Grid = TT*8 blocks: block does
// (t = b>>3, rows seg*512..seg*512+511), x_t staged in LDS (32KB).
// ---------------------------------------------------------------------------
__launch_bounds__(256)
__global__ void k_gax(const float* x, const int* ell_col, const float* ell_val,
                      const int* ell_cnt, float* gax) {
  int t = blockIdx.x >> 3;
  int seg = blockIdx.x & 7;
  __shared__ float xs[NN * 2];
  const float* xt = x + (size_t)t * NN * 2;
  for (int i = threadIdx.x; i < NN * 2; i += 256) xs[i] = xt[i];
  __syncthreads();
  int base = seg * 512 * 2;
  for (int oo = threadIdx.x; oo < 512 * 2; oo += 256) {
    int o = base + oo;
    int r = o >> 1, cmp = o & 1;
    int cnt = ell_cnt[r];
    const int* cp = ell_col + (size_t)r * CAP;
    const float* vp = ell_val + (size_t)r * CAP;
    float acc = 0.0f;
    for (int j = 0; j < cnt; j += 4) {
      acc += vp[j]     * xs[cp[j]     * 2 + cmp];
      acc += vp[j + 1] * xs[cp[j + 1] * 2 + cmp];
      acc += vp[j + 2] * xs[cp[j + 2] * 2 + cmp];
      acc += vp[j + 3] * xs[cp[j + 3] * 2 + cmp];
    }
    gax[(size_t)t * NN * 2 + o] = acc;
  }
}

// ---------------------------------------------------------------------------
// Cell 0, fully fused. Gather uses register-resident ELL chunks + __shfl
// broadcast: lane j of the wave holds slot j's (col,val); __shfl(.,m) feeds
// each gathered 256B row-load. All gathers are independent -> deep vmcnt
// pipelining (this was the R3 bottleneck: per-slot global idx loads made a
// ~400-600cyc serial chain per nnz).
// ---------------------------------------------------------------------------
__launch_bounds__(256)
__global__ void k_cell0(const int* __restrict__ ell_col, const float* __restrict__ ell_val,
                        const int* __restrict__ ell_cnt,
                        const float* __restrict__ h0r, float* __restrict__ h0w,
                        float* __restrict__ c0,
                        const float* __restrict__ xt, const float* __restrict__ gaxt,
                        const float* __restrict__ gcWi, const float* __restrict__ liWi,
                        const float* __restrict__ gcWh, const float* __restrict__ liWh,
                        const float* __restrict__ bias) {
  const int row0 = blockIdx.x * 8;
  const int tid = threadIdx.x;
  const int wave = tid >> 6, lane = tid & 63;
  __shared__ float g0s[8][64];
  __shared__ float hs[8][64];
  __shared__ float xg[8][4];     // [rr][0..1]=x, [2..3]=gax
  __shared__ float combS[8][256];

  // --- gather phase: wave w does rows w and w+4 ---
  for (int half = 0; half < 2; half++) {
    int rr = wave + half * 4;
    int r = row0 + rr;
    int cnt = ell_cnt[r];
    const int* cp = ell_col + (size_t)r * CAP;
    const float* vp = ell_val + (size_t)r * CAP;
    float acc = 0.0f;
    for (int j0 = 0; j0 < cnt; j0 += 64) {
      int myc = cp[j0 + lane];      // coalesced 256B chunk loads (no guard: CAP=3*64)
      float myv = vp[j0 + lane];
      int lim = cnt - j0; if (lim > 64) lim = 64;   // lim is a multiple of 4
      for (int m = 0; m < lim; m += 4) {
        int cA = __shfl(myc, m),     cB = __shfl(myc, m + 1);
        int cC = __shfl(myc, m + 2), cD = __shfl(myc, m + 3);
        float vA = __shfl(myv, m),     vB = __shfl(myv, m + 1);
        float vC = __shfl(myv, m + 2), vD = __shfl(myv, m + 3);
        acc += vA * h0r[(size_t)cA * HH + lane];
        acc += vB * h0r[(size_t)cB * HH + lane];
        acc += vC * h0r[(size_t)cC * HH + lane];
        acc += vD * h0r[(size_t)cD * HH + lane];
      }
    }
    g0s[rr][lane] = acc;
  }
  // --- stage local tiles ---
  for (int i = tid; i < 512; i += 256) (&hs[0][0])[i] = h0r[(size_t)row0 * HH + i];
  if (tid < 16) {
    int rr = tid >> 1, cc = tid & 1;
    xg[rr][cc] = xt[(size_t)(row0 + rr) * 2 + cc];
    xg[rr][2 + cc] = gaxt[(size_t)(row0 + rr) * 2 + cc];
  }
  __syncthreads();

  // --- dense phase: thread = one output column, 8 rows ---
  const int col = tid;
  float acc[8];
  {
    float b = bias[col];
    float wg0 = gcWi[col], wg1 = gcWi[GG + col];
    float wl0 = liWi[col], wl1 = liWi[GG + col];
#pragma unroll
    for (int r = 0; r < 8; r++)
      acc[r] = b + xg[r][2] * wg0 + xg[r][3] * wg1 + xg[r][0] * wl0 + xg[r][1] * wl1;
  }
  for (int k = 0; k < 64; k += 4) {
    float wg[4], wl[4];
#pragma unroll
    for (int i = 0; i < 4; i++) {
      wg[i] = gcWh[(k + i) * GG + col];
      wl[i] = liWh[(k + i) * GG + col];
    }
#pragma unroll
    for (int r = 0; r < 8; r++) {
      float4 gv = *reinterpret_cast<const float4*>(&g0s[r][k]);
      float4 hv = *reinterpret_cast<const float4*>(&hs[r][k]);
      acc[r] += gv.x * wg[0] + gv.y * wg[1] + gv.z * wg[2] + gv.w * wg[3]
              + hv.x * wl[0] + hv.y * wl[1] + hv.z * wl[2] + hv.w * wl[3];
    }
  }
#pragma unroll
  for (int r = 0; r < 8; r++) combS[r][col] = acc[r];
  __syncthreads();

  // --- gate phase: 512 (row, hcol) outputs, 2 per thread, coalesced ---
#pragma unroll
  for (int p = 0; p < 2; p++) {
    int o = tid + p * 256;
    int rr = o >> 6, hc = o & 63;
    float ig = combS[rr][hc], fg = combS[rr][hc + 64];
    float og = combS[rr][hc + 128], gg = combS[rr][hc + 192];
    size_t gi = (size_t)row0 * HH + o;
    float cprev = c0[gi];
    float si = 1.0f / (1.0f + __expf(-ig));
    float sf = 1.0f / (1.0f + __expf(-fg));
    float so = 1.0f / (1.0f + __expf(-og));
    float cn = sf * cprev + si * tanhf(gg);
    float hn = so * tanhf(cn);
    c0[gi] = cn;
    h0w[gi] = hn;
  }
}

// ---------------------------------------------------------------------------
// Cell 1, fully fused: dual gather (A@h0_new, A@h1) sharing ELL registers.
// ---------------------------------------------------------------------------
__launch_bounds__(256)
__global__ void k_cell1(const int* __restrict__ ell_col, const float* __restrict__ ell_val,
                        const int* __restrict__ ell_cnt,
                        const float* __restrict__ h0n,
                        const float* __restrict__ h1r, float* __restrict__ h1w,
                        float* __restrict__ c1,
                        const float* __restrict__ gcWi, const float* __restrict__ liWi,
                        const float* __restrict__ gcWh, const float* __restrict__ liWh,
                        const float* __restrict__ bias) {
  const int row0 = blockIdx.x * 8;
  const int tid = threadIdx.x;
  const int wave = tid >> 6, lane = tid & 63;
  __shared__ float gis[8][64];   // A@h0n
  __shared__ float ghs[8][64];   // A@h1
  __shared__ float h0s[8][64];
  __shared__ float h1s[8][64];
  __shared__ float combS[8][256];

  for (int half = 0; half < 2; half++) {
    int rr = wave + half * 4;
    int r = row0 + rr;
    int cnt = ell_cnt[r];
    const int* cp = ell_col + (size_t)r * CAP;
    const float* vp = ell_val + (size_t)r * CAP;
    float a0 = 0.0f, a1 = 0.0f;
    for (int j0 = 0; j0 < cnt; j0 += 64) {
      int myc = cp[j0 + lane];
      float myv = vp[j0 + lane];
      int lim = cnt - j0; if (lim > 64) lim = 64;
      for (int m = 0; m < lim; m += 2) {
        int cA = __shfl(myc, m), cB = __shfl(myc, m + 1);
        float vA = __shfl(myv, m), vB = __shfl(myv, m + 1);
        a0 += vA * h0n[(size_t)cA * HH + lane];
        a1 += vA * h1r[(size_t)cA * HH + lane];
        a0 += vB * h0n[(size_t)cB * HH + lane];
        a1 += vB * h1r[(size_t)cB * HH + lane];
      }
    }
    gis[rr][lane] = a0;
    ghs[rr][lane] = a1;
  }
  for (int i = tid; i < 512; i += 256) {
    (&h0s[0][0])[i] = h0n[(size_t)row0 * HH + i];
    (&h1s[0][0])[i] = h1r[(size_t)row0 * HH + i];
  }
  __syncthreads();

  const int col = tid;
  float acc[8];
  {
    float b = bias[col];
#pragma unroll
    for (int r = 0; r < 8; r++) acc[r] = b;
  }
  for (int k = 0; k < 64; k += 4) {
    float w0[4], w1[4], w2[4], w3[4];
#pragma unroll
    for (int i = 0; i < 4; i++) {
      w0[i] = gcWi[(k + i) * GG + col];
      w1[i] = liWi[(k + i) * GG + col];
      w2[i] = gcWh[(k + i) * GG + col];
      w3[i] = liWh[(k + i) * GG + col];
    }
#pragma unroll
    for (int r = 0; r < 8; r++) {
      float4 av = *reinterpret_cast<const float4*>(&gis[r][k]);
      float4 bv = *reinterpret_cast<const float4*>(&h0s[r][k]);
      float4 cv = *reinterpret_cast<const float4*>(&ghs[r][k]);
      float4 dv = *reinterpret_cast<const float4*>(&h1s[r][k]);
      acc[r] += av.x * w0[0] + av.y * w0[1] + av.z * w0[2] + av.w * w0[3]
              + bv.x * w1[0] + bv.y * w1[1] + bv.z * w1[2] + bv.w * w1[3]
              + cv.x * w2[0] + cv.y * w2[1] + cv.z * w2[2] + cv.w * w2[3]
              + dv.x * w3[0] + dv.y * w3[1] + dv.z * w3[2] + dv.w * w3[3];
    }
  }
#pragma unroll
  for (int r = 0; r < 8; r++) combS[r][col] = acc[r];
  __syncthreads();

#pragma unroll
  for (int p = 0; p < 2; p++) {
    int o = tid + p * 256;
    int rr = o >> 6, hc = o & 63;
    float ig = combS[rr][hc], fg = combS[rr][hc + 64];
    float og = combS[rr][hc + 128], gg = combS[rr][hc + 192];
    size_t gi = (size_t)row0 * HH + o;
    float cprev = c1[gi];
    float si = 1.0f / (1.0f + __expf(-ig));
    float sf = 1.0f / (1.0f + __expf(-fg));
    float so = 1.0f / (1.0f + __expf(-og));
    float cn = sf * cprev + si * tanhf(gg);
    float hn = so * tanhf(cn);
    c1[gi] = cn;
    h1w[gi] = hn;
  }
}

// ---------------------------------------------------------------------------
// Output projection: out[r,p] = h1[r,:] @ outW[:,p] + outb[p].
// ---------------------------------------------------------------------------
__launch_bounds__(256)
__global__ void k_out(const float* __restrict__ h1, const float* __restrict__ outW,
                      const float* __restrict__ outb, float* __restrict__ out) {
  int idx = blockIdx.x * 256 + threadIdx.x;
  if (idx >= NN * PP) return;
  int r = idx / PP, p = idx - r * PP;
  float acc = outb[p];
  const float* hrow = h1 + (size_t)r * HH;
#pragma unroll 16
  for (int k = 0; k < HH; k++) acc += hrow[k] * outW[k * PP + p];
  out[idx] = acc;
}

extern "C" void kernel_launch(void* const* d_in, const int* in_sizes, int n_in,
                              void* d_out, int out_size, void* d_ws, size_t ws_size,
                              hipStream_t stream) {
  const float* x     = (const float*)d_in[0];
  const float* adj   = (const float*)d_in[1];
  const float* gcWi0 = (const float*)d_in[2];
  const float* gcbi0 = (const float*)d_in[3];
  const float* gcWh0 = (const float*)d_in[4];
  const float* gcbh0 = (const float*)d_in[5];
  const float* liWi0 = (const float*)d_in[6];
  const float* libi0 = (const float*)d_in[7];
  const float* liWh0 = (const float*)d_in[8];
  const float* libh0 = (const float*)d_in[9];
  const float* gcWi1 = (const float*)d_in[10];
  const float* gcbi1 = (const float*)d_in[11];
  const float* gcWh1 = (const float*)d_in[12];
  const float* gcbh1 = (const float*)d_in[13];
  const float* liWi1 = (const float*)d_in[14];
  const float* libi1 = (const float*)d_in[15];
  const float* liWh1 = (const float*)d_in[16];
  const float* libh1 = (const float*)d_in[17];
  const float* outW  = (const float*)d_in[18];
  const float* outb  = (const float*)d_in[19];

  char* ws = (char*)d_ws;
  size_t off = 0;
  auto carve = [&](size_t bytes) {
    void* p = ws + off;
    off += (bytes + 255) & ~(size_t)255;
    return p;
  };
  float* dinv    = (float*)carve((size_t)NN * 4);
  int*   ell_col = (int*)carve((size_t)NN * CAP * 4);
  float* ell_val = (float*)carve((size_t)NN * CAP * 4);
  int*   ell_cnt = (int*)carve((size_t)NN * 4);
  float* bias    = (float*)carve((size_t)2 * GG * 4);
  float* state   = (float*)carve((size_t)6 * NN * HH * 4);
  float* gax     = (float*)carve((size_t)TT * NN * 2 * 4);

  float* h0buf[2] = {state, state + NN * HH};
  float* h1buf[2] = {state + 2 * NN * HH, state + 3 * NN * HH};
  float* c0 = state + 4 * NN * HH;
  float* c1 = state + 5 * NN * HH;

  k_prep<<<512, 256, 0, stream>>>(gcbi0, gcbh0, libi0, libh0,
                                  gcbi1, gcbh1, libi1, libh1, bias, state);
  k_build<<<NN, 256, 0, stream>>>(adj, dinv, ell_col, ell_val, ell_cnt);
  k_scale<<<(NN * CAP) / 256, 256, 0, stream>>>(dinv, ell_col, ell_val);
  k_gax<<<TT * 8, 256, 0, stream>>>(x, ell_col, ell_val, ell_cnt, gax);

  for (int t = 0; t < TT; t++) {
    int cur = t & 1;
    k_cell0<<<NN / 8, 256, 0, stream>>>(
        ell_col, ell_val, ell_cnt,
        h0buf[cur], h0buf[cur ^ 1], c0,
        x + (size_t)t * NN * 2, gax + (size_t)t * NN * 2,
        gcWi0, liWi0, gcWh0, liWh0, bias);
    k_cell1<<<NN / 8, 256, 0, stream>>>(
        ell_col, ell_val, ell_cnt,
        h0buf[cur ^ 1],
        h1buf[cur], h1buf[cur ^ 1], c1,
        gcWi1, liWi1, gcWh1, liWh1, bias + GG);
  }

  k_out<<<(NN * PP + 255) / 256, 256, 0, stream>>>(h1buf[0], outW, outb, (float*)d_out);
}